// Round 1
// baseline (1176.895 us; speedup 1.0000x reference)
//
#include <hip/hip_runtime.h>
#include <math.h>

#define NB 32768
#define H 320
#define V 34
#define G4 (4 * H)       // 1280
#define ROWS 16          // rows per block
#define NTHREADS 320     // one thread per h-index

// ws layout (floats):
//   gate_table [V][G4]  : embed_W @ W_ih^T + b_ih + b_hh        (43520)
//   C2         [V][H]   : joint_W @ pred_W                      (10880)
//   jb2        [V]      : joint_b + joint_W @ pred_b            (34)
#define WS_GT 0
#define WS_C2 (V * G4)
#define WS_JB (V * G4 + V * H)
#define WS_TOTAL (V * G4 + V * H + V)

__device__ __forceinline__ float sigf(float x) {
    return 1.0f / (1.0f + __expf(-x));
}
__device__ __forceinline__ float tanh_fast(float x) {
    // tanh(x) = 1 - 2/(exp(2x)+1); correct limits at +-inf
    return 1.0f - 2.0f / (1.0f + __expf(2.0f * x));
}

__global__ void build_tables(const float* __restrict__ embed_W,
                             const float* __restrict__ W_ih,
                             const float* __restrict__ b_ih,
                             const float* __restrict__ b_hh,
                             const float* __restrict__ pred_W,
                             const float* __restrict__ pred_b,
                             const float* __restrict__ joint_W,
                             const float* __restrict__ joint_b,
                             float* __restrict__ ws) {
    int tid = blockIdx.x * blockDim.x + threadIdx.x;
    if (tid < V * G4) {
        // gate_table[v][j]
        int v = tid / G4, j = tid % G4;
        float acc = b_ih[j] + b_hh[j];
        const float* e = embed_W + v * H;
        const float* w = W_ih + (size_t)j * H;
        for (int k = 0; k < H; k += 4) {
            float4 e4 = *(const float4*)(e + k);
            float4 w4 = *(const float4*)(w + k);
            acc = fmaf(e4.x, w4.x, acc);
            acc = fmaf(e4.y, w4.y, acc);
            acc = fmaf(e4.z, w4.z, acc);
            acc = fmaf(e4.w, w4.w, acc);
        }
        ws[WS_GT + tid] = acc;
    } else if (tid < V * G4 + V * H) {
        // C2[v][k] = sum_j joint_W[v][j] * pred_W[j][k]
        int t2 = tid - V * G4;
        int v = t2 / H, k = t2 % H;
        float acc = 0.0f;
        for (int j = 0; j < H; ++j)
            acc = fmaf(joint_W[v * H + j], pred_W[(size_t)j * H + k], acc);
        ws[tid] = acc;
    } else if (tid < WS_TOTAL) {
        int v = tid - V * G4 - V * H;
        float acc = joint_b[v];
        for (int j = 0; j < H; ++j)
            acc = fmaf(joint_W[v * H + j], pred_b[j], acc);
        ws[tid] = acc;
    }
}

__launch_bounds__(NTHREADS)
__global__ void rnnt_main(const int* __restrict__ x,
                          const float* __restrict__ enc,
                          const float* __restrict__ h_in,
                          const float* __restrict__ c_in,
                          const float* __restrict__ W_hh,
                          const float* __restrict__ ws,
                          const float* __restrict__ joint_W,
                          float* __restrict__ out) {
    const float* gt  = ws + WS_GT;
    const float* C2  = ws + WS_C2;
    const float* jb2 = ws + WS_JB;
    float* dec_out = out;                          // [NB] (argmax as float)
    float* hn_out  = out + NB;                     // [NB*H]
    float* cn_out  = out + NB + (size_t)NB * H;    // [NB*H]

    const int row0 = blockIdx.x * ROWS;
    const int t = threadIdx.x;   // h-index k this thread owns

    __shared__ float hn_lds[ROWS][H];
    __shared__ float logits_lds[ROWS][V];

    // thread t owns gate columns {t, t+H, t+2H, t+3H}  -> i,f,g,o for k=t
    float acc[ROWS][4];
    #pragma unroll
    for (int r = 0; r < ROWS; ++r) {
        int xv = x[row0 + r];                      // wave-uniform
        const float* g = gt + (size_t)xv * G4;
        acc[r][0] = g[t];
        acc[r][1] = g[H + t];
        acc[r][2] = g[2 * H + t];
        acc[r][3] = g[3 * H + t];
    }

    const float* wr0 = W_hh + (size_t)t * H;              // row j = t
    const float* wr1 = wr0 + (size_t)H * H;               // row j = t+H
    const float* wr2 = wr0 + (size_t)2 * H * H;
    const float* wr3 = wr0 + (size_t)3 * H * H;

    for (int k = 0; k < H; k += 4) {
        const float4 w0 = *(const float4*)(wr0 + k);
        const float4 w1 = *(const float4*)(wr1 + k);
        const float4 w2 = *(const float4*)(wr2 + k);
        const float4 w3 = *(const float4*)(wr3 + k);
        #pragma unroll
        for (int r = 0; r < ROWS; ++r) {
            // wave-uniform h read (expect s_load_dwordx4)
            const float4 hv = *(const float4*)(h_in + (size_t)(row0 + r) * H + k);
            acc[r][0] = fmaf(hv.w, w0.w, fmaf(hv.z, w0.z, fmaf(hv.y, w0.y, fmaf(hv.x, w0.x, acc[r][0]))));
            acc[r][1] = fmaf(hv.w, w1.w, fmaf(hv.z, w1.z, fmaf(hv.y, w1.y, fmaf(hv.x, w1.x, acc[r][1]))));
            acc[r][2] = fmaf(hv.w, w2.w, fmaf(hv.z, w2.z, fmaf(hv.y, w2.y, fmaf(hv.x, w2.x, acc[r][2]))));
            acc[r][3] = fmaf(hv.w, w3.w, fmaf(hv.z, w3.z, fmaf(hv.y, w3.y, fmaf(hv.x, w3.x, acc[r][3]))));
        }
    }

    // LSTM cell, fully in-register per (row, k=t)
    #pragma unroll
    for (int r = 0; r < ROWS; ++r) {
        size_t idx = (size_t)(row0 + r) * H + t;
        float ig = sigf(acc[r][0]);
        float fg = sigf(acc[r][1]);
        float gg = tanh_fast(acc[r][2]);
        float og = sigf(acc[r][3]);
        float cn = fmaf(fg, c_in[idx], ig * gg);
        float hn = og * tanh_fast(cn);
        cn_out[idx] = cn;
        hn_out[idx] = hn;
        hn_lds[r][t] = hn;
    }
    __syncthreads();

    // joint: logits[r][v] = jb2[v] + enc[r].joint_W[v] + hn[r].C2[v]
    for (int task = t; task < ROWS * V; task += NTHREADS) {
        int r = task / V, v = task % V;
        float accL = jb2[v];
        const float* er = enc + (size_t)(row0 + r) * H;
        const float* jw = joint_W + (size_t)v * H;
        const float* c2 = C2 + (size_t)v * H;
        for (int k = 0; k < H; k += 4) {
            float4 e4 = *(const float4*)(er + k);
            float4 j4 = *(const float4*)(jw + k);
            float4 h4 = *(const float4*)(&hn_lds[r][k]);
            float4 c4 = *(const float4*)(c2 + k);
            accL = fmaf(e4.x, j4.x, accL); accL = fmaf(h4.x, c4.x, accL);
            accL = fmaf(e4.y, j4.y, accL); accL = fmaf(h4.y, c4.y, accL);
            accL = fmaf(e4.z, j4.z, accL); accL = fmaf(h4.z, c4.z, accL);
            accL = fmaf(e4.w, j4.w, accL); accL = fmaf(h4.w, c4.w, accL);
        }
        logits_lds[r][v] = accL;
    }
    __syncthreads();

    // argmax (numpy semantics: first max wins -> strict >)
    if (t < ROWS) {
        int best = 0;
        float bv = logits_lds[t][0];
        for (int v = 1; v < V; ++v) {
            float lv = logits_lds[t][v];
            if (lv > bv) { bv = lv; best = v; }
        }
        dec_out[row0 + t] = (float)best;
    }
}

extern "C" void kernel_launch(void* const* d_in, const int* in_sizes, int n_in,
                              void* d_out, int out_size, void* d_ws, size_t ws_size,
                              hipStream_t stream) {
    const int*   x       = (const int*)  d_in[0];
    const float* enc     = (const float*)d_in[1];
    const float* h       = (const float*)d_in[2];
    const float* c       = (const float*)d_in[3];
    const float* embed_W = (const float*)d_in[4];
    const float* W_ih    = (const float*)d_in[5];
    const float* W_hh    = (const float*)d_in[6];
    const float* b_ih    = (const float*)d_in[7];
    const float* b_hh    = (const float*)d_in[8];
    const float* pred_W  = (const float*)d_in[9];
    const float* pred_b  = (const float*)d_in[10];
    const float* joint_W = (const float*)d_in[11];
    const float* joint_b = (const float*)d_in[12];
    float* out = (float*)d_out;
    float* ws  = (float*)d_ws;

    int tblocks = (WS_TOTAL + 255) / 256;
    build_tables<<<tblocks, 256, 0, stream>>>(embed_W, W_ih, b_ih, b_hh,
                                              pred_W, pred_b, joint_W, joint_b, ws);
    rnnt_main<<<NB / ROWS, NTHREADS, 0, stream>>>(x, enc, h, c, W_hh, ws, joint_W, out);
}

// Round 2
// 521.008 us; speedup vs baseline: 2.2589x; 2.2589x over previous
//
#include <hip/hip_runtime.h>
#include <math.h>

#define NB 32768
#define H 320
#define V 34
#define N4 1280            // 4*H, GEMM N dimension
#define BM 128
#define BN 128
#define BK 16
#define MB_BLOCKS (NB / BM)   // 256
#define NB_BLOCKS (N4 / BN)   // 10
#define NWG (MB_BLOCKS * NB_BLOCKS)  // 2560

// ws layout (floats):
//   gt_p [V][N4]   : permuted gate table; col n=4*hk+g <-> orig col g*H+hk
//                    value = b_ih+b_hh+embed_W[v]·W_ih[orig]          (43520)
//   C2t  [80][136] : C2t[kc][v*4+ki] = (joint_W@pred_W)[v][kc*4+ki]  (10880)
//   jb2  [34]      : joint_b + joint_W@pred_b
#define WS_GTP 0
#define WS_C2T (V * N4)                 // 43520
#define WS_JB2 (V * N4 + 80 * 136)      // 54400
#define WS_TOTAL (WS_JB2 + 34)          // 54434

__device__ __forceinline__ float sigf(float x) {
    return 1.0f / (1.0f + __expf(-x));
}
__device__ __forceinline__ float tanh_fast(float x) {
    return 1.0f - 2.0f / (1.0f + __expf(2.0f * x));
}

__global__ void build_tables(const float* __restrict__ embed_W,
                             const float* __restrict__ W_ih,
                             const float* __restrict__ b_ih,
                             const float* __restrict__ b_hh,
                             const float* __restrict__ pred_W,
                             const float* __restrict__ pred_b,
                             const float* __restrict__ joint_W,
                             const float* __restrict__ joint_b,
                             float* __restrict__ ws) {
    int tid = blockIdx.x * blockDim.x + threadIdx.x;
    if (tid < V * N4) {
        // permuted gate table
        int v = tid / N4, n = tid % N4;
        int orig = (n & 3) * H + (n >> 2);       // gate-major row index
        float acc = b_ih[orig] + b_hh[orig];
        const float* e = embed_W + (size_t)v * H;
        const float* w = W_ih + (size_t)orig * H;
        for (int k = 0; k < H; k += 4) {
            float4 e4 = *(const float4*)(e + k);
            float4 w4 = *(const float4*)(w + k);
            acc = fmaf(e4.x, w4.x, acc);
            acc = fmaf(e4.y, w4.y, acc);
            acc = fmaf(e4.z, w4.z, acc);
            acc = fmaf(e4.w, w4.w, acc);
        }
        ws[WS_GTP + tid] = acc;
    } else if (tid < WS_JB2) {
        // C2t[kc][v*4+ki] = sum_j joint_W[v][j] * pred_W[j][k], k=kc*4+ki
        int idx = tid - WS_C2T;
        int kc = idx / 136, r = idx % 136;
        int v = r >> 2, ki = r & 3;
        int k = kc * 4 + ki;
        float acc = 0.0f;
        for (int j = 0; j < H; ++j)
            acc = fmaf(joint_W[(size_t)v * H + j], pred_W[(size_t)j * H + k], acc);
        ws[tid] = acc;
    } else if (tid < WS_TOTAL) {
        int v = tid - WS_JB2;
        float acc = joint_b[v];
        for (int j = 0; j < H; ++j)
            acc = fmaf(joint_W[(size_t)v * H + j], pred_b[j], acc);
        ws[tid] = acc;
    }
}

// gates GEMM (h @ Wp^T, Wp = gate-interleaved W_hh) + fused LSTM cell
__launch_bounds__(256, 4)
__global__ void lstm_gemm(const int* __restrict__ x,
                          const float* __restrict__ h_in,
                          const float* __restrict__ c_in,
                          const float* __restrict__ W_hh,
                          const float* __restrict__ ws,
                          float* __restrict__ out) {
    __shared__ float Alds[BK][BM];
    __shared__ float Blds[BK][BN];

    // XCD-bijective swizzle: logical l -> contiguous chunks per XCD.
    // NWG = 2560 = 8 * 320.
    int l = (blockIdx.x & 7) * (NWG / 8) + (blockIdx.x >> 3);
    const int mb = l / NB_BLOCKS;          // m fastest within a chunk
    const int nb = l % NB_BLOCKS;
    const int row0 = mb * BM, n0 = nb * BN;
    const int tid = threadIdx.x;
    const int tx = tid & 15, ty = tid >> 4;

    float* hn_out = out + NB;
    float* cn_out = out + NB + (size_t)NB * H;

    // accumulator init from permuted gate table
    const float* gtp = ws + WS_GTP;
    float acc[8][8];
    #pragma unroll
    for (int i = 0; i < 8; ++i) {
        int m = row0 + tx * 8 + i;
        int xv = x[m];
        const float* g = gtp + (size_t)xv * N4 + n0 + ty * 8;
        float4 g0 = *(const float4*)g;
        float4 g1 = *(const float4*)(g + 4);
        acc[i][0] = g0.x; acc[i][1] = g0.y; acc[i][2] = g0.z; acc[i][3] = g0.w;
        acc[i][4] = g1.x; acc[i][5] = g1.y; acc[i][6] = g1.z; acc[i][7] = g1.w;
    }

    for (int kc = 0; kc < H; kc += BK) {
        // stage A (h rows) and B (gate-permuted W_hh rows), coalesced
        #pragma unroll
        for (int ee = 0; ee < 2; ++ee) {
            int e = tid + ee * 256;
            int ra = e >> 2, kq = e & 3;
            float4 va = *(const float4*)(h_in + (size_t)(row0 + ra) * H + kc + kq * 4);
            Alds[kq * 4 + 0][ra] = va.x;
            Alds[kq * 4 + 1][ra] = va.y;
            Alds[kq * 4 + 2][ra] = va.z;
            Alds[kq * 4 + 3][ra] = va.w;
            int n = n0 + ra;
            int orig = (n & 3) * H + (n >> 2);
            float4 vb = *(const float4*)(W_hh + (size_t)orig * H + kc + kq * 4);
            Blds[kq * 4 + 0][ra] = vb.x;
            Blds[kq * 4 + 1][ra] = vb.y;
            Blds[kq * 4 + 2][ra] = vb.z;
            Blds[kq * 4 + 3][ra] = vb.w;
        }
        __syncthreads();

        #pragma unroll
        for (int k = 0; k < BK; ++k) {
            float4 a0 = *(const float4*)&Alds[k][tx * 8];
            float4 a1 = *(const float4*)&Alds[k][tx * 8 + 4];
            float4 b0 = *(const float4*)&Blds[k][ty * 8];
            float4 b1 = *(const float4*)&Blds[k][ty * 8 + 4];
            float a[8] = {a0.x, a0.y, a0.z, a0.w, a1.x, a1.y, a1.z, a1.w};
            float b[8] = {b0.x, b0.y, b0.z, b0.w, b1.x, b1.y, b1.z, b1.w};
            #pragma unroll
            for (int i = 0; i < 8; ++i)
                #pragma unroll
                for (int j = 0; j < 8; ++j)
                    acc[i][j] = fmaf(a[i], b[j], acc[i][j]);
        }
        __syncthreads();
    }

    // LSTM epilogue: cols n0+ty*8 .. +7 = h-indices hk0, hk0+1 with all 4 gates
    const int hk0 = n0 / 4 + ty * 2;
    #pragma unroll
    for (int i = 0; i < 8; ++i) {
        int m = row0 + tx * 8 + i;
        float2 cv = *(const float2*)(c_in + (size_t)m * H + hk0);
        float ig0 = sigf(acc[i][0]);
        float fg0 = sigf(acc[i][1]);
        float gg0 = tanh_fast(acc[i][2]);
        float og0 = sigf(acc[i][3]);
        float cn0 = fmaf(fg0, cv.x, ig0 * gg0);
        float hn0 = og0 * tanh_fast(cn0);
        float ig1 = sigf(acc[i][4]);
        float fg1 = sigf(acc[i][5]);
        float gg1 = tanh_fast(acc[i][6]);
        float og1 = sigf(acc[i][7]);
        float cn1 = fmaf(fg1, cv.y, ig1 * gg1);
        float hn1 = og1 * tanh_fast(cn1);
        *(float2*)(hn_out + (size_t)m * H + hk0) = make_float2(hn0, hn1);
        *(float2*)(cn_out + (size_t)m * H + hk0) = make_float2(cn0, cn1);
    }
}

// joint + argmax: one thread per row; J-matrix reads are wave-uniform -> s_load
__launch_bounds__(256)
__global__ void joint_argmax(const float* __restrict__ enc,
                             const float* __restrict__ joint_W,
                             const float* __restrict__ ws,
                             float* __restrict__ out) {
    const int r = blockIdx.x * 256 + threadIdx.x;
    const float* hn = out + NB;           // written by lstm_gemm
    const float* C2t = ws + WS_C2T;
    const float* jb2 = ws + WS_JB2;

    float acc[V];
    #pragma unroll
    for (int v = 0; v < V; ++v) acc[v] = jb2[v];

    // enc @ joint_W^T
    const float* er = enc + (size_t)r * H;
    for (int kc = 0; kc < H; kc += 4) {
        float4 e4 = *(const float4*)(er + kc);
        #pragma unroll
        for (int v = 0; v < V; ++v) {
            const float* jw = joint_W + (size_t)v * H + kc;   // uniform address
            acc[v] = fmaf(e4.w, jw[3],
                     fmaf(e4.z, jw[2],
                     fmaf(e4.y, jw[1],
                     fmaf(e4.x, jw[0], acc[v]))));
        }
    }
    // hn @ C2^T  (C2t chunk layout: [kc][v*4+ki], contiguous -> s_load friendly)
    const float* hr = hn + (size_t)r * H;
    for (int kc = 0; kc < 80; ++kc) {
        float4 e4 = *(const float4*)(hr + kc * 4);
        const float* ct = C2t + kc * 136;                     // uniform address
        #pragma unroll
        for (int v = 0; v < V; ++v) {
            acc[v] = fmaf(e4.w, ct[v * 4 + 3],
                     fmaf(e4.z, ct[v * 4 + 2],
                     fmaf(e4.y, ct[v * 4 + 1],
                     fmaf(e4.x, ct[v * 4 + 0], acc[v]))));
        }
    }

    // numpy argmax: first max wins -> strict >
    int best = 0;
    float bv = acc[0];
    #pragma unroll
    for (int v = 1; v < V; ++v) {
        if (acc[v] > bv) { bv = acc[v]; best = v; }
    }
    out[r] = (float)best;
}

extern "C" void kernel_launch(void* const* d_in, const int* in_sizes, int n_in,
                              void* d_out, int out_size, void* d_ws, size_t ws_size,
                              hipStream_t stream) {
    const int*   x       = (const int*)  d_in[0];
    const float* enc     = (const float*)d_in[1];
    const float* h       = (const float*)d_in[2];
    const float* c       = (const float*)d_in[3];
    const float* embed_W = (const float*)d_in[4];
    const float* W_ih    = (const float*)d_in[5];
    const float* W_hh    = (const float*)d_in[6];
    const float* b_ih    = (const float*)d_in[7];
    const float* b_hh    = (const float*)d_in[8];
    const float* pred_W  = (const float*)d_in[9];
    const float* pred_b  = (const float*)d_in[10];
    const float* joint_W = (const float*)d_in[11];
    const float* joint_b = (const float*)d_in[12];
    float* out = (float*)d_out;
    float* ws  = (float*)d_ws;

    int tblocks = (WS_TOTAL + 255) / 256;
    build_tables<<<tblocks, 256, 0, stream>>>(embed_W, W_ih, b_ih, b_hh,
                                              pred_W, pred_b, joint_W, joint_b, ws);
    lstm_gemm<<<NWG, 256, 0, stream>>>(x, h, c, W_hh, ws, out);
    joint_argmax<<<NB / 256, 256, 0, stream>>>(enc, joint_W, ws, out);
}

// Round 3
// 324.723 us; speedup vs baseline: 3.6243x; 1.6045x over previous
//
#include <hip/hip_runtime.h>
#include <math.h>

#define NB 32768
#define H 320
#define V 34
#define N4 1280            // 4*H
#define BM 128
#define BN 128
#define BK 32
#define KSTEPS (H / BK)    // 10
#define NWG ((NB / BM) * (N4 / BN))   // 2560

typedef _Float16 f16;
typedef f16 f16x4 __attribute__((ext_vector_type(4)));
typedef f16 f16x8 __attribute__((ext_vector_type(8)));
typedef float f32x4 __attribute__((ext_vector_type(4)));

// ws layout:
//   floats: gtp [V][N4] permuted gate table (bias+emb@W_ih)   @0      (43520)
//           C2  [V][H]  joint_W @ pred_W                      @43520  (10880)
//           jb2 [V]     joint_b + joint_W @ pred_b            @54400  (34)
//   halves (byte offset 217744, 16B aligned):
//           Wp1 [N4][H] fp16 hi-plane of gate-permuted W_hh
//           Wp2 [N4][H] fp16 lo-plane ((w - w1)*2048)
#define WS_GTP 0
#define WS_C2 43520
#define WS_JB2 54400
#define WS_HALF_BYTE 217744
#define WP_COUNT (N4 * H)          // 409600 per plane
#define BUILD_T0 43520             // gtp count
#define BUILD_T1 54400             // + C2
#define BUILD_T2 54434             // + jb2
#define BUILD_TOTAL (BUILD_T2 + WP_COUNT)   // 464034

__device__ __forceinline__ float sigf(float x) {
    return 1.0f / (1.0f + __expf(-x));
}
__device__ __forceinline__ float tanh_fast(float x) {
    return 1.0f - 2.0f / (1.0f + __expf(2.0f * x));
}

__global__ void build_tables(const float* __restrict__ embed_W,
                             const float* __restrict__ W_ih,
                             const float* __restrict__ b_ih,
                             const float* __restrict__ b_hh,
                             const float* __restrict__ pred_W,
                             const float* __restrict__ pred_b,
                             const float* __restrict__ joint_W,
                             const float* __restrict__ joint_b,
                             const float* __restrict__ W_hh,
                             float* __restrict__ ws) {
    int tid = blockIdx.x * blockDim.x + threadIdx.x;
    if (tid < BUILD_T0) {
        // permuted gate table: col n -> orig row (n&3)*H + (n>>2)
        int v = tid / N4, n = tid % N4;
        int orig = (n & 3) * H + (n >> 2);
        float acc = b_ih[orig] + b_hh[orig];
        const float* e = embed_W + (size_t)v * H;
        const float* w = W_ih + (size_t)orig * H;
        for (int k = 0; k < H; k += 4) {
            float4 e4 = *(const float4*)(e + k);
            float4 w4 = *(const float4*)(w + k);
            acc = fmaf(e4.x, w4.x, acc);
            acc = fmaf(e4.y, w4.y, acc);
            acc = fmaf(e4.z, w4.z, acc);
            acc = fmaf(e4.w, w4.w, acc);
        }
        ws[WS_GTP + tid] = acc;
    } else if (tid < BUILD_T1) {
        // C2[v][k] = sum_j joint_W[v][j] * pred_W[j][k]
        int idx = tid - BUILD_T0;
        int v = idx / H, k = idx % H;
        float acc = 0.0f;
        for (int j = 0; j < H; ++j)
            acc = fmaf(joint_W[(size_t)v * H + j], pred_W[(size_t)j * H + k], acc);
        ws[tid] = acc;
    } else if (tid < BUILD_T2) {
        int v = tid - BUILD_T1;
        float acc = joint_b[v];
        for (int j = 0; j < H; ++j)
            acc = fmaf(joint_W[(size_t)v * H + j], pred_b[j], acc);
        ws[tid] = acc;
    } else if (tid < BUILD_TOTAL) {
        // fp16 split planes of gate-permuted W_hh
        int idx = tid - BUILD_T2;
        int n = idx / H, k = idx % H;
        int orig = (n & 3) * H + (n >> 2);
        float wv = W_hh[(size_t)orig * H + k];
        f16 w1 = (f16)wv;
        f16 w2 = (f16)((wv - (float)w1) * 2048.0f);
        f16* wp1 = (f16*)((char*)ws + WS_HALF_BYTE);
        wp1[idx] = w1;
        wp1[WP_COUNT + idx] = w2;
    }
}

__device__ __forceinline__ void stage_tile(int w, int lane, int m0, int n0, int kc,
                                           const float* __restrict__ h_in,
                                           const f16* __restrict__ Wp1,
                                           const f16* __restrict__ Wp2,
                                           f16* A1, f16* A2, f16* B1, f16* B2) {
    // A: 128 rows x 32 k, fp32 source -> split to 2 fp16 planes
    #pragma unroll
    for (int i = 0; i < 4; ++i) {
        int r = (w * 4 + i) * 8 + (lane >> 3);
        int cf = (lane & 7) * 4;
        float4 hv = *(const float4*)(h_in + (size_t)(m0 + r) * H + kc + cf);
        f16x4 h1v, h2v;
        f16 a;
        a = (f16)hv.x; h1v[0] = a; h2v[0] = (f16)((hv.x - (float)a) * 2048.0f);
        a = (f16)hv.y; h1v[1] = a; h2v[1] = (f16)((hv.y - (float)a) * 2048.0f);
        a = (f16)hv.z; h1v[2] = a; h2v[2] = (f16)((hv.z - (float)a) * 2048.0f);
        a = (f16)hv.w; h1v[3] = a; h2v[3] = (f16)((hv.w - (float)a) * 2048.0f);
        *(f16x4*)(A1 + r * 32 + cf) = h1v;
        *(f16x4*)(A2 + r * 32 + cf) = h2v;
    }
    // B: 128 rows x 32 k, already-split fp16 planes, straight copy
    #pragma unroll
    for (int i = 0; i < 2; ++i) {
        int nrow = (w * 2 + i) * 16 + (lane >> 2);
        int kh = (lane & 3) * 8;
        *(int4*)(B1 + nrow * 32 + kh) =
            *(const int4*)(Wp1 + (size_t)(n0 + nrow) * H + kc + kh);
        *(int4*)(B2 + nrow * 32 + kh) =
            *(const int4*)(Wp2 + (size_t)(n0 + nrow) * H + kc + kh);
    }
}

__launch_bounds__(256, 2)
__global__ void lstm_gemm(const int* __restrict__ x,
                          const float* __restrict__ h_in,
                          const float* __restrict__ c_in,
                          const float* __restrict__ ws,
                          float* __restrict__ out) {
    __shared__ __align__(16) char smem[65536];
    const int tid = threadIdx.x, lane = tid & 63, w = tid >> 6;

    int l = (blockIdx.x & 7) * (NWG / 8) + (blockIdx.x >> 3);  // XCD chunks
    const int mb = l / (N4 / BN);   // n-fastest within chunk -> A L2-resident
    const int nb = l % (N4 / BN);
    const int m0 = mb * BM, n0 = nb * BN;

    const f16* Wp1 = (const f16*)((const char*)ws + WS_HALF_BYTE);
    const f16* Wp2 = Wp1 + WP_COUNT;
    const float* gtp = ws + WS_GTP;
    float* hn_out = out + NB;
    float* cn_out = out + NB + (size_t)NB * H;

    f16* base = (f16*)smem;   // per buffer (32KB): A1,A2,B1,B2 of 4096 halves each

    f32x4 accM[4][4], accC[4][4];
    #pragma unroll
    for (int i = 0; i < 4; ++i)
        #pragma unroll
        for (int j = 0; j < 4; ++j) {
            accM[i][j] = (f32x4){0.f, 0.f, 0.f, 0.f};
            accC[i][j] = (f32x4){0.f, 0.f, 0.f, 0.f};
        }

    stage_tile(w, lane, m0, n0, 0, h_in, Wp1, Wp2,
               base, base + 4096, base + 8192, base + 12288);
    __syncthreads();

    const int wm = (w >> 1) * 64, wn = (w & 1) * 64;
    int cur = 0;
    for (int t = 0; t < KSTEPS; ++t) {
        if (t < KSTEPS - 1) {
            f16* nb_ = base + (cur ^ 1) * 16384;
            stage_tile(w, lane, m0, n0, (t + 1) * BK, h_in, Wp1, Wp2,
                       nb_, nb_ + 4096, nb_ + 8192, nb_ + 12288);
        }
        f16* A1 = base + cur * 16384;
        f16* A2 = A1 + 4096;
        f16* B1 = A1 + 8192;
        f16* B2 = A1 + 12288;
        const int ar = (lane & 15) * 32 + (lane >> 4) * 8;

        f16x8 a[4], b1[4], b2[4];
        #pragma unroll
        for (int mi = 0; mi < 4; ++mi)
            a[mi] = *(const f16x8*)(A1 + (wm + mi * 16) * 32 + ar);
        #pragma unroll
        for (int nj = 0; nj < 4; ++nj)
            b1[nj] = *(const f16x8*)(B1 + (wn + nj * 16) * 32 + ar);
        #pragma unroll
        for (int mi = 0; mi < 4; ++mi)
            #pragma unroll
            for (int nj = 0; nj < 4; ++nj)
                accM[mi][nj] = __builtin_amdgcn_mfma_f32_16x16x32_f16(
                    a[mi], b1[nj], accM[mi][nj], 0, 0, 0);
        #pragma unroll
        for (int nj = 0; nj < 4; ++nj)
            b2[nj] = *(const f16x8*)(B2 + (wn + nj * 16) * 32 + ar);
        #pragma unroll
        for (int mi = 0; mi < 4; ++mi)
            #pragma unroll
            for (int nj = 0; nj < 4; ++nj)
                accC[mi][nj] = __builtin_amdgcn_mfma_f32_16x16x32_f16(
                    a[mi], b2[nj], accC[mi][nj], 0, 0, 0);
        #pragma unroll
        for (int mi = 0; mi < 4; ++mi)
            a[mi] = *(const f16x8*)(A2 + (wm + mi * 16) * 32 + ar);
        #pragma unroll
        for (int mi = 0; mi < 4; ++mi)
            #pragma unroll
            for (int nj = 0; nj < 4; ++nj)
                accC[mi][nj] = __builtin_amdgcn_mfma_f32_16x16x32_f16(
                    a[mi], b1[nj], accC[mi][nj], 0, 0, 0);
        __syncthreads();
        cur ^= 1;
    }

    // merge split accumulators and stage gates[m][n] in LDS (64KB, reuses bufs)
    float* gates = (float*)smem;
    #pragma unroll
    for (int mi = 0; mi < 4; ++mi)
        #pragma unroll
        for (int nj = 0; nj < 4; ++nj) {
            f32x4 vm = accM[mi][nj];
            f32x4 vc = accC[mi][nj];
            int n = wn + nj * 16 + (lane & 15);
            int mb4 = wm + mi * 16 + (lane >> 4) * 4;
            #pragma unroll
            for (int q = 0; q < 4; ++q)
                gates[(mb4 + q) * 128 + n] = fmaf(vc[q], 1.0f / 2048.0f, vm[q]);
        }
    __syncthreads();

    // phase 2: LSTM cell + coalesced writes. 4096 outputs = 128 m x 32 hk
    const int hk0 = n0 >> 2;
    #pragma unroll 4
    for (int it = 0; it < 16; ++it) {
        int idx = it * 256 + tid;
        int ml = idx >> 5, hkl = idx & 31;
        f32x4 g4 = *(const f32x4*)&gates[ml * 128 + hkl * 4];
        int m = m0 + ml;
        int hk = hk0 + hkl;
        int xv = x[m];
        float4 b4 = *(const float4*)(gtp + (size_t)xv * N4 + n0 + hkl * 4);
        float ig = sigf(g4[0] + b4.x);
        float fg = sigf(g4[1] + b4.y);
        float gg = tanh_fast(g4[2] + b4.z);
        float og = sigf(g4[3] + b4.w);
        float cv = c_in[(size_t)m * H + hk];
        float cn = fmaf(fg, cv, ig * gg);
        float hn = og * tanh_fast(cn);
        hn_out[(size_t)m * H + hk] = hn;
        cn_out[(size_t)m * H + hk] = cn;
    }
}

// joint + argmax: 128 rows/block, k split across enc-part and hn-part waves
__launch_bounds__(256)
__global__ void joint_argmax(const float* __restrict__ enc,
                             const float* __restrict__ joint_W,
                             const float* __restrict__ ws,
                             float* __restrict__ out) {
    __shared__ float part[128][35];
    const float* C2 = ws + WS_C2;
    const float* jb2 = ws + WS_JB2;
    const float* hn = out + NB;

    const int tid = threadIdx.x, lane = tid & 63, w = tid >> 6;
    const int rloc = (w >> 1) * 64 + lane;
    const int r = blockIdx.x * 128 + rloc;
    const int kh = w & 1;
    const float* Arow = (kh ? hn : enc) + (size_t)r * H;
    const float* Wt = kh ? C2 : joint_W;

    float acc[V];
    #pragma unroll
    for (int v = 0; v < V; ++v) acc[v] = 0.0f;

    for (int k = 0; k < H; k += 4) {
        float4 e4 = *(const float4*)(Arow + k);
        #pragma unroll
        for (int v = 0; v < V; ++v) {
            const float* wr = Wt + (size_t)v * H + k;   // wave-uniform -> s_load
            acc[v] = fmaf(e4.w, wr[3],
                     fmaf(e4.z, wr[2],
                     fmaf(e4.y, wr[1],
                     fmaf(e4.x, wr[0], acc[v]))));
        }
    }

    if (kh) {
        #pragma unroll
        for (int v = 0; v < V; ++v) part[rloc][v] = acc[v];
    }
    __syncthreads();
    if (!kh) {
        float best = -1e30f;
        int bi = 0;
        #pragma unroll
        for (int v = 0; v < V; ++v) {
            float t2 = acc[v] + part[rloc][v] + jb2[v];
            if (t2 > best) { best = t2; bi = v; }   // strict > : first max wins
        }
        out[r] = (float)bi;
    }
}

extern "C" void kernel_launch(void* const* d_in, const int* in_sizes, int n_in,
                              void* d_out, int out_size, void* d_ws, size_t ws_size,
                              hipStream_t stream) {
    const int*   x       = (const int*)  d_in[0];
    const float* enc     = (const float*)d_in[1];
    const float* h       = (const float*)d_in[2];
    const float* c       = (const float*)d_in[3];
    const float* embed_W = (const float*)d_in[4];
    const float* W_ih    = (const float*)d_in[5];
    const float* W_hh    = (const float*)d_in[6];
    const float* b_ih    = (const float*)d_in[7];
    const float* b_hh    = (const float*)d_in[8];
    const float* pred_W  = (const float*)d_in[9];
    const float* pred_b  = (const float*)d_in[10];
    const float* joint_W = (const float*)d_in[11];
    const float* joint_b = (const float*)d_in[12];
    float* out = (float*)d_out;
    float* ws  = (float*)d_ws;

    int tblocks = (BUILD_TOTAL + 255) / 256;
    build_tables<<<tblocks, 256, 0, stream>>>(embed_W, W_ih, b_ih, b_hh,
                                              pred_W, pred_b, joint_W, joint_b,
                                              W_hh, ws);
    lstm_gemm<<<NWG, 256, 0, stream>>>(x, h, c, ws, out);
    joint_argmax<<<NB / 128, 256, 0, stream>>>(enc, joint_W, ws, out);
}

// Round 4
// 166.019 us; speedup vs baseline: 7.0889x; 1.9559x over previous
//
#include <hip/hip_runtime.h>
#include <math.h>

#define NB 32768
#define H 320
#define V 34
#define N4 1280            // 4*H
#define BM 128
#define BN 128
#define BK 32
#define KSTEPS (H / BK)    // 10
#define NWG ((NB / BM) * (N4 / BN))   // 2560

typedef _Float16 f16;
typedef f16 f16x4 __attribute__((ext_vector_type(4)));
typedef f16 f16x8 __attribute__((ext_vector_type(8)));
typedef float f32x4 __attribute__((ext_vector_type(4)));

// ws layout:
//   floats: gtp [V][N4] permuted gate table (bias+emb@W_ih)   @0      (43520)
//           C2  [V][H]  joint_W @ pred_W                      @43520  (10880)
//           jb2 [V]     joint_b + joint_W @ pred_b            @54400  (34)
//   halves (byte offset 217744, 16B aligned):
//           Wp1 [N4][H]  fp16 hi-plane of gate-permuted W_hh
//           Wp2 [N4][H]  fp16 lo-plane ((w - w1)*2048)
//   halves (byte offset 1856144, 16B aligned):
//           Jp1 [48][640] fp16 hi-plane of [joint_W | C2], rows 34..47 zero
//           Jp2 [48][640] fp16 lo-plane
#define WS_GTP 0
#define WS_C2 43520
#define WS_JB2 54400
#define WS_HALF_BYTE 217744
#define WP_COUNT (N4 * H)          // 409600 per plane
#define WS_JP_BYTE 1856144
#define JP_COUNT (48 * 640)        // 30720 per plane
#define BUILD_T0 43520             // gtp count
#define BUILD_T1 54400             // + C2
#define BUILD_T2 54434             // + jb2
#define BUILD_TOTAL (BUILD_T2 + WP_COUNT)   // 464034

// joint GEMM geometry
#define JBM 64
#define JBN 48
#define JBK 32
#define JKSTEPS 20                 // 640 / 32

__device__ __forceinline__ float sigf(float x) {
    return 1.0f / (1.0f + __expf(-x));
}
__device__ __forceinline__ float tanh_fast(float x) {
    return 1.0f - 2.0f / (1.0f + __expf(2.0f * x));
}

__global__ void build_tables(const float* __restrict__ embed_W,
                             const float* __restrict__ W_ih,
                             const float* __restrict__ b_ih,
                             const float* __restrict__ b_hh,
                             const float* __restrict__ pred_W,
                             const float* __restrict__ pred_b,
                             const float* __restrict__ joint_W,
                             const float* __restrict__ joint_b,
                             const float* __restrict__ W_hh,
                             float* __restrict__ ws) {
    int tid = blockIdx.x * blockDim.x + threadIdx.x;
    if (tid < BUILD_T0) {
        // permuted gate table: col n -> orig row (n&3)*H + (n>>2)
        int v = tid / N4, n = tid % N4;
        int orig = (n & 3) * H + (n >> 2);
        float acc = b_ih[orig] + b_hh[orig];
        const float* e = embed_W + (size_t)v * H;
        const float* w = W_ih + (size_t)orig * H;
        for (int k = 0; k < H; k += 4) {
            float4 e4 = *(const float4*)(e + k);
            float4 w4 = *(const float4*)(w + k);
            acc = fmaf(e4.x, w4.x, acc);
            acc = fmaf(e4.y, w4.y, acc);
            acc = fmaf(e4.z, w4.z, acc);
            acc = fmaf(e4.w, w4.w, acc);
        }
        ws[WS_GTP + tid] = acc;
    } else if (tid < BUILD_T1) {
        // C2[v][k] = sum_j joint_W[v][j] * pred_W[j][k]
        int idx = tid - BUILD_T0;
        int v = idx / H, k = idx % H;
        float acc = 0.0f;
        for (int j = 0; j < H; ++j)
            acc = fmaf(joint_W[(size_t)v * H + j], pred_W[(size_t)j * H + k], acc);
        ws[tid] = acc;
    } else if (tid < BUILD_T2) {
        int v = tid - BUILD_T1;
        float acc = joint_b[v];
        for (int j = 0; j < H; ++j)
            acc = fmaf(joint_W[(size_t)v * H + j], pred_b[j], acc);
        ws[tid] = acc;
    } else if (tid < BUILD_TOTAL) {
        // fp16 split planes of gate-permuted W_hh
        int idx = tid - BUILD_T2;
        int n = idx / H, k = idx % H;
        int orig = (n & 3) * H + (n >> 2);
        float wv = W_hh[(size_t)orig * H + k];
        f16 w1 = (f16)wv;
        f16 w2 = (f16)((wv - (float)w1) * 2048.0f);
        f16* wp1 = (f16*)((char*)ws + WS_HALF_BYTE);
        wp1[idx] = w1;
        wp1[WP_COUNT + idx] = w2;
    }
}

// fp16 split planes of [joint_W | C2] with zero padding rows 34..47
// (separate kernel: needs C2, which build_tables writes)
__global__ void build_joint(const float* __restrict__ joint_W,
                            float* __restrict__ ws) {
    int tid = blockIdx.x * blockDim.x + threadIdx.x;
    if (tid >= JP_COUNT) return;
    int n = tid / 640, k = tid % 640;
    float wv = 0.0f;
    if (n < V)
        wv = (k < H) ? joint_W[(size_t)n * H + k] : ws[WS_C2 + (size_t)n * H + (k - H)];
    f16 w1 = (f16)wv;
    f16 w2 = (f16)((wv - (float)w1) * 2048.0f);
    f16* jp1 = (f16*)((char*)ws + WS_JP_BYTE);
    jp1[tid] = w1;
    jp1[JP_COUNT + tid] = w2;
}

__device__ __forceinline__ void stage_tile(int w, int lane, int m0, int n0, int kc,
                                           const float* __restrict__ h_in,
                                           const f16* __restrict__ Wp1,
                                           const f16* __restrict__ Wp2,
                                           f16* A1, f16* A2, f16* B1, f16* B2) {
    // A: 128 rows x 32 k, fp32 source -> split to 2 fp16 planes
    #pragma unroll
    for (int i = 0; i < 4; ++i) {
        int r = (w * 4 + i) * 8 + (lane >> 3);
        int cf = (lane & 7) * 4;
        float4 hv = *(const float4*)(h_in + (size_t)(m0 + r) * H + kc + cf);
        f16x4 h1v, h2v;
        f16 a;
        a = (f16)hv.x; h1v[0] = a; h2v[0] = (f16)((hv.x - (float)a) * 2048.0f);
        a = (f16)hv.y; h1v[1] = a; h2v[1] = (f16)((hv.y - (float)a) * 2048.0f);
        a = (f16)hv.z; h1v[2] = a; h2v[2] = (f16)((hv.z - (float)a) * 2048.0f);
        a = (f16)hv.w; h1v[3] = a; h2v[3] = (f16)((hv.w - (float)a) * 2048.0f);
        *(f16x4*)(A1 + r * 32 + cf) = h1v;
        *(f16x4*)(A2 + r * 32 + cf) = h2v;
    }
    // B: 128 rows x 32 k, already-split fp16 planes, straight copy
    #pragma unroll
    for (int i = 0; i < 2; ++i) {
        int nrow = (w * 2 + i) * 16 + (lane >> 2);
        int kh = (lane & 3) * 8;
        *(int4*)(B1 + nrow * 32 + kh) =
            *(const int4*)(Wp1 + (size_t)(n0 + nrow) * H + kc + kh);
        *(int4*)(B2 + nrow * 32 + kh) =
            *(const int4*)(Wp2 + (size_t)(n0 + nrow) * H + kc + kh);
    }
}

__launch_bounds__(256, 2)
__global__ void lstm_gemm(const int* __restrict__ x,
                          const float* __restrict__ h_in,
                          const float* __restrict__ c_in,
                          const float* __restrict__ ws,
                          float* __restrict__ out) {
    __shared__ __align__(16) char smem[65536];
    const int tid = threadIdx.x, lane = tid & 63, w = tid >> 6;

    int l = (blockIdx.x & 7) * (NWG / 8) + (blockIdx.x >> 3);  // XCD chunks
    const int mb = l / (N4 / BN);   // n-fastest within chunk -> A L2-resident
    const int nb = l % (N4 / BN);
    const int m0 = mb * BM, n0 = nb * BN;

    const f16* Wp1 = (const f16*)((const char*)ws + WS_HALF_BYTE);
    const f16* Wp2 = Wp1 + WP_COUNT;
    const float* gtp = ws + WS_GTP;
    float* hn_out = out + NB;
    float* cn_out = out + NB + (size_t)NB * H;

    f16* base = (f16*)smem;   // per buffer (32KB): A1,A2,B1,B2 of 4096 halves each

    f32x4 accM[4][4], accC[4][4];
    #pragma unroll
    for (int i = 0; i < 4; ++i)
        #pragma unroll
        for (int j = 0; j < 4; ++j) {
            accM[i][j] = (f32x4){0.f, 0.f, 0.f, 0.f};
            accC[i][j] = (f32x4){0.f, 0.f, 0.f, 0.f};
        }

    stage_tile(w, lane, m0, n0, 0, h_in, Wp1, Wp2,
               base, base + 4096, base + 8192, base + 12288);
    __syncthreads();

    const int wm = (w >> 1) * 64, wn = (w & 1) * 64;
    int cur = 0;
    for (int t = 0; t < KSTEPS; ++t) {
        if (t < KSTEPS - 1) {
            f16* nb_ = base + (cur ^ 1) * 16384;
            stage_tile(w, lane, m0, n0, (t + 1) * BK, h_in, Wp1, Wp2,
                       nb_, nb_ + 4096, nb_ + 8192, nb_ + 12288);
        }
        f16* A1 = base + cur * 16384;
        f16* A2 = A1 + 4096;
        f16* B1 = A1 + 8192;
        f16* B2 = A1 + 12288;
        const int ar = (lane & 15) * 32 + (lane >> 4) * 8;

        f16x8 a[4], b1[4], b2[4];
        #pragma unroll
        for (int mi = 0; mi < 4; ++mi)
            a[mi] = *(const f16x8*)(A1 + (wm + mi * 16) * 32 + ar);
        #pragma unroll
        for (int nj = 0; nj < 4; ++nj)
            b1[nj] = *(const f16x8*)(B1 + (wn + nj * 16) * 32 + ar);
        #pragma unroll
        for (int mi = 0; mi < 4; ++mi)
            #pragma unroll
            for (int nj = 0; nj < 4; ++nj)
                accM[mi][nj] = __builtin_amdgcn_mfma_f32_16x16x32_f16(
                    a[mi], b1[nj], accM[mi][nj], 0, 0, 0);
        #pragma unroll
        for (int nj = 0; nj < 4; ++nj)
            b2[nj] = *(const f16x8*)(B2 + (wn + nj * 16) * 32 + ar);
        #pragma unroll
        for (int mi = 0; mi < 4; ++mi)
            #pragma unroll
            for (int nj = 0; nj < 4; ++nj)
                accC[mi][nj] = __builtin_amdgcn_mfma_f32_16x16x32_f16(
                    a[mi], b2[nj], accC[mi][nj], 0, 0, 0);
        #pragma unroll
        for (int mi = 0; mi < 4; ++mi)
            a[mi] = *(const f16x8*)(A2 + (wm + mi * 16) * 32 + ar);
        #pragma unroll
        for (int mi = 0; mi < 4; ++mi)
            #pragma unroll
            for (int nj = 0; nj < 4; ++nj)
                accC[mi][nj] = __builtin_amdgcn_mfma_f32_16x16x32_f16(
                    a[mi], b1[nj], accC[mi][nj], 0, 0, 0);
        __syncthreads();
        cur ^= 1;
    }

    // merge split accumulators and stage gates[m][n] in LDS (64KB, reuses bufs)
    float* gates = (float*)smem;
    #pragma unroll
    for (int mi = 0; mi < 4; ++mi)
        #pragma unroll
        for (int nj = 0; nj < 4; ++nj) {
            f32x4 vm = accM[mi][nj];
            f32x4 vc = accC[mi][nj];
            int n = wn + nj * 16 + (lane & 15);
            int mb4 = wm + mi * 16 + (lane >> 4) * 4;
            #pragma unroll
            for (int q = 0; q < 4; ++q)
                gates[(mb4 + q) * 128 + n] = fmaf(vc[q], 1.0f / 2048.0f, vm[q]);
        }
    __syncthreads();

    // phase 2: LSTM cell + coalesced writes. 4096 outputs = 128 m x 32 hk
    const int hk0 = n0 >> 2;
    #pragma unroll 4
    for (int it = 0; it < 16; ++it) {
        int idx = it * 256 + tid;
        int ml = idx >> 5, hkl = idx & 31;
        f32x4 g4 = *(const f32x4*)&gates[ml * 128 + hkl * 4];
        int m = m0 + ml;
        int hk = hk0 + hkl;
        int xv = x[m];
        float4 b4 = *(const float4*)(gtp + (size_t)xv * N4 + n0 + hkl * 4);
        float ig = sigf(g4[0] + b4.x);
        float fg = sigf(g4[1] + b4.y);
        float gg = tanh_fast(g4[2] + b4.z);
        float og = sigf(g4[3] + b4.w);
        float cv = c_in[(size_t)m * H + hk];
        float cn = fmaf(fg, cv, ig * gg);
        float hn = og * tanh_fast(cn);
        hn_out[(size_t)m * H + hk] = hn;
        cn_out[(size_t)m * H + hk] = cn;
    }
}

// joint + argmax as an MFMA GEMM: logits = [enc | hn] @ [joint_W | C2]^T
// 64 rows/block, K=640 in 20 double-buffered steps, fp16-split numerics.
__launch_bounds__(256, 2)
__global__ void joint_argmax(const float* __restrict__ enc,
                             const float* __restrict__ ws,
                             float* __restrict__ out) {
    // per buffer: A1[2048] A2[2048] B1[1536] B2[1536] halves = 14336 B
    __shared__ __align__(16) char smem[28672];
    const int tid = threadIdx.x, lane = tid & 63, w = tid >> 6;
    const int m0 = blockIdx.x * JBM;

    const f16* Jp1 = (const f16*)((const char*)ws + WS_JP_BYTE);
    const f16* Jp2 = Jp1 + JP_COUNT;
    const float* hn = out + NB;
    const float* jb2 = ws + WS_JB2;

    f16* base = (f16*)smem;

    f32x4 accM[3], accC[3];
    #pragma unroll
    for (int j = 0; j < 3; ++j) {
        accM[j] = (f32x4){0.f, 0.f, 0.f, 0.f};
        accC[j] = (f32x4){0.f, 0.f, 0.f, 0.f};
    }

    // ---- staging helper (lambda): K-step t -> buffer buf
    auto stage = [&](int t, f16* A1, f16* A2, f16* B1, f16* B2) {
        const float* src = (t < 10) ? enc : hn;
        const int off = (t % 10) * JBK;
        // A: 64 rows x 32 k : 2 iters x 256 threads x float4
        #pragma unroll
        for (int i = 0; i < 2; ++i) {
            int r = (w * 2 + i) * 8 + (lane >> 3);
            int cf = (lane & 7) * 4;
            float4 hv = *(const float4*)(src + (size_t)(m0 + r) * H + off + cf);
            f16x4 h1v, h2v;
            f16 a;
            a = (f16)hv.x; h1v[0] = a; h2v[0] = (f16)((hv.x - (float)a) * 2048.0f);
            a = (f16)hv.y; h1v[1] = a; h2v[1] = (f16)((hv.y - (float)a) * 2048.0f);
            a = (f16)hv.z; h1v[2] = a; h2v[2] = (f16)((hv.z - (float)a) * 2048.0f);
            a = (f16)hv.w; h1v[3] = a; h2v[3] = (f16)((hv.w - (float)a) * 2048.0f);
            *(f16x4*)(A1 + r * 32 + cf) = h1v;
            *(f16x4*)(A2 + r * 32 + cf) = h2v;
        }
        // B: 48 rows x 32 k from [48][640] planes; threads 0..191
        if (tid < 192) {
            int n = tid >> 2, kh = (tid & 3) * 8;
            size_t gsrc = (size_t)n * 640 + t * JBK + kh;
            *(int4*)(B1 + n * 32 + kh) = *(const int4*)(Jp1 + gsrc);
            *(int4*)(B2 + n * 32 + kh) = *(const int4*)(Jp2 + gsrc);
        }
    };

    stage(0, base, base + 2048, base + 4096, base + 5632);
    __syncthreads();

    const int wm = w * 16;
    int cur = 0;
    for (int t = 0; t < JKSTEPS; ++t) {
        if (t < JKSTEPS - 1) {
            f16* nb_ = base + (cur ^ 1) * 7168;
            stage(t + 1, nb_, nb_ + 2048, nb_ + 4096, nb_ + 5632);
        }
        f16* A1 = base + cur * 7168;
        f16* A2 = A1 + 2048;
        f16* B1 = A1 + 4096;
        f16* B2 = A1 + 5632;
        const int ar = (lane & 15) * 32 + (lane >> 4) * 8;

        f16x8 a1 = *(const f16x8*)(A1 + wm * 32 + ar);
        f16x8 a2 = *(const f16x8*)(A2 + wm * 32 + ar);
        f16x8 b1[3], b2[3];
        #pragma unroll
        for (int nj = 0; nj < 3; ++nj) {
            b1[nj] = *(const f16x8*)(B1 + nj * 16 * 32 + ar);
            b2[nj] = *(const f16x8*)(B2 + nj * 16 * 32 + ar);
        }
        #pragma unroll
        for (int nj = 0; nj < 3; ++nj) {
            accM[nj] = __builtin_amdgcn_mfma_f32_16x16x32_f16(a1, b1[nj], accM[nj], 0, 0, 0);
            accC[nj] = __builtin_amdgcn_mfma_f32_16x16x32_f16(a1, b2[nj], accC[nj], 0, 0, 0);
            accC[nj] = __builtin_amdgcn_mfma_f32_16x16x32_f16(a2, b1[nj], accC[nj], 0, 0, 0);
        }
        __syncthreads();
        cur ^= 1;
    }

    // merge -> logits LDS [64][49] (stride 49: conflict-free column reads)
    float* lg = (float*)smem;
    #pragma unroll
    for (int nj = 0; nj < 3; ++nj) {
        int n = nj * 16 + (lane & 15);
        int mr = wm + (lane >> 4) * 4;
        #pragma unroll
        for (int q = 0; q < 4; ++q)
            lg[(mr + q) * 49 + n] = fmaf(accC[nj][q], 1.0f / 2048.0f, accM[nj][q]);
    }
    __syncthreads();

    // argmax per row (numpy: first max wins -> strict >)
    if (tid < JBM) {
        const float* row = lg + tid * 49;
        float best = row[0] + jb2[0];
        int bi = 0;
        #pragma unroll
        for (int v = 1; v < V; ++v) {
            float t2 = row[v] + jb2[v];
            if (t2 > best) { best = t2; bi = v; }
        }
        out[m0 + tid] = (float)bi;
    }
}

extern "C" void kernel_launch(void* const* d_in, const int* in_sizes, int n_in,
                              void* d_out, int out_size, void* d_ws, size_t ws_size,
                              hipStream_t stream) {
    const int*   x       = (const int*)  d_in[0];
    const float* enc     = (const float*)d_in[1];
    const float* h       = (const float*)d_in[2];
    const float* c       = (const float*)d_in[3];
    const float* embed_W = (const float*)d_in[4];
    const float* W_ih    = (const float*)d_in[5];
    const float* W_hh    = (const float*)d_in[6];
    const float* b_ih    = (const float*)d_in[7];
    const float* b_hh    = (const float*)d_in[8];
    const float* pred_W  = (const float*)d_in[9];
    const float* pred_b  = (const float*)d_in[10];
    const float* joint_W = (const float*)d_in[11];
    const float* joint_b = (const float*)d_in[12];
    float* out = (float*)d_out;
    float* ws  = (float*)d_ws;

    int tblocks = (BUILD_TOTAL + 255) / 256;
    build_tables<<<tblocks, 256, 0, stream>>>(embed_W, W_ih, b_ih, b_hh,
                                              pred_W, pred_b, joint_W, joint_b,
                                              W_hh, ws);
    build_joint<<<(JP_COUNT + 255) / 256, 256, 0, stream>>>(joint_W, ws);
    lstm_gemm<<<NWG, 256, 0, stream>>>(x, h, c, ws, out);
    joint_argmax<<<NB / JBM, 256, 0, stream>>>(enc, ws, out);
}